// Round 17
// baseline (102.799 us; speedup 1.0000x reference)
//
#include <hip/hip_runtime.h>
#include <hip/hip_bf16.h>
#include <math.h>

// Problem constants
#define TT       16
#define NSEQ     256
#define TOK      4096
#define DMODEL   512
#define DINNER   1024
#define DSTATE   64
#define NHEADS   16
#define HEADDIM  64
#define DINPROJ  2192
#define DTOFF    2176
#define ZLD      2176    // zb row stride (z:0..1023, x:1024..2047, BC:2048..2175)

using bf16x8 = __attribute__((ext_vector_type(8))) short;
using f32x4  = __attribute__((ext_vector_type(4))) float;
typedef __hip_bfloat16 bf16;

__device__ __forceinline__ void gload_lds16(const void* g, void* l) {
    __builtin_amdgcn_global_load_lds(
        (const __attribute__((address_space(1))) unsigned int*)g,
        (__attribute__((address_space(3))) unsigned int*)l,
        16, 0, 0);
}

// ---------------------------------------------------------------------------
// GEMM core (bf16 sources via global_load_lds):
// C[M][N] = A[M][K]*B[N][K]^T (+ bias[col]), bf16 out.
// Tile 128 x (NFRAG*32), BK=32, 256 threads (4 waves, 2x2 wave grid).
// ---------------------------------------------------------------------------
template<int NFRAG>
__device__ __forceinline__ void gemm_core(
    short* As, short* Bs,
    const bf16* __restrict__ A, const bf16* __restrict__ B,
    const float* __restrict__ bias, bf16* __restrict__ Ch,
    int bm, int bn, int K, int lda, int ldb, int ldc, int Nreal)
{
    constexpr int BN = NFRAG * 32;
    const int tid = threadIdx.x;
    const int wv = tid >> 6, ln = tid & 63;
    const int m0 = bm * 128, n0 = bn * BN;
    const int wr = wv >> 1, wc = wv & 1;
    const int lr = ln & 15, lk = (ln >> 4) * 8;

    f32x4 acc[4][NFRAG];
#pragma unroll
    for (int m = 0; m < 4; ++m)
#pragma unroll
        for (int n = 0; n < NFRAG; ++n) acc[m][n] = (f32x4){0.f, 0.f, 0.f, 0.f};

    for (int k0 = 0; k0 < K; k0 += 32) {
        __syncthreads();
#pragma unroll
        for (int r = 0; r < 2; ++r) {
            const int ofs = r * 4096 + tid * 16;
            const int row = ofs >> 6, ke = (ofs & 63) >> 1;
            gload_lds16(A + (size_t)(m0 + row) * lda + k0 + ke, (char*)As + ofs);
        }
#pragma unroll
        for (int r = 0; r < NFRAG / 2; ++r) {
            const int ofs = r * 4096 + tid * 16;
            const int row = ofs >> 6, ke = (ofs & 63) >> 1;
            gload_lds16(B + (size_t)(n0 + row) * ldb + k0 + ke, (char*)Bs + ofs);
        }
        __syncthreads();

        bf16x8 af[4], bfr[NFRAG];
#pragma unroll
        for (int m = 0; m < 4; ++m)
            af[m] = *(const bf16x8*)&As[(wr * 64 + m * 16 + lr) * 32 + lk];
#pragma unroll
        for (int n = 0; n < NFRAG; ++n)
            bfr[n] = *(const bf16x8*)&Bs[(wc * (BN / 2) + n * 16 + lr) * 32 + lk];
#pragma unroll
        for (int m = 0; m < 4; ++m)
#pragma unroll
            for (int n = 0; n < NFRAG; ++n)
                acc[m][n] = __builtin_amdgcn_mfma_f32_16x16x32_bf16(
                    af[m], bfr[n], acc[m][n], 0, 0, 0);
    }

    const int mBase = m0 + wr * 64, nBase = n0 + wc * (BN / 2);
    float cbv[NFRAG];
#pragma unroll
    for (int n = 0; n < NFRAG; ++n) {
        const int col = nBase + n * 16 + lr;
        cbv[n] = (bias != nullptr && col < Nreal) ? bias[col] : 0.f;
    }
#pragma unroll
    for (int m = 0; m < 4; ++m) {
#pragma unroll
        for (int j = 0; j < 4; ++j) {
            const int row = mBase + m * 16 + (ln >> 4) * 4 + j;
#pragma unroll
            for (int n = 0; n < NFRAG; ++n) {
                const int col = nBase + n * 16 + lr;
                if (col < Nreal)
                    Ch[(size_t)row * ldc + col] =
                        __float2bfloat16(acc[m][n][j] + cbv[n]);
            }
        }
    }
}

// ---------------------------------------------------------------------------
// GEMM core with fp32 sources (register-staged, converted to bf16 in-flight):
//   A(m,k) = A[(m0+m)*lda + k]                         (fp32 row-major)
//   B(n,k) = Bsrc[k*ldb + n0+n] * (SCALE? scale[n0+n]) (fp32 TRANSPOSED src)
// C bf16 out, no bias. Tile 128 x 64 (NFRAG=2), BK=32.
// ---------------------------------------------------------------------------
template<bool SCALE>
__device__ __forceinline__ void gemm_f32t(
    short* As, short* Bs,
    const float* __restrict__ A, const float* __restrict__ Bsrc,
    const float* __restrict__ scale, bf16* __restrict__ Ch,
    int bm, int bn, int K, int lda, int ldb, int ldc)
{
    const int tid = threadIdx.x;
    const int wv = tid >> 6, ln = tid & 63;
    const int m0 = bm * 128, n0 = bn * 64;
    const int wr = wv >> 1, wc = wv & 1;
    const int lr = ln & 15, lk = (ln >> 4) * 8;

    const int bn_row = tid >> 2;
    const float bscale = SCALE ? scale[n0 + bn_row] : 1.f;

    f32x4 acc[4][2];
#pragma unroll
    for (int m = 0; m < 4; ++m)
#pragma unroll
        for (int n = 0; n < 2; ++n) acc[m][n] = (f32x4){0.f, 0.f, 0.f, 0.f};

    for (int k0 = 0; k0 < K; k0 += 32) {
        __syncthreads();
        {   // A tile: thread -> row tid>>1, k-offset (tid&1)*16 (4x float4)
            const int row = tid >> 1, koff = (tid & 1) * 16;
            const float* src = A + (size_t)(m0 + row) * lda + k0 + koff;
#pragma unroll
            for (int q = 0; q < 4; ++q) {
                const float4 v = *(const float4*)(src + q * 4);
                As[row * 32 + koff + q * 4 + 0] = (short)__bfloat16_as_ushort(__float2bfloat16(v.x));
                As[row * 32 + koff + q * 4 + 1] = (short)__bfloat16_as_ushort(__float2bfloat16(v.y));
                As[row * 32 + koff + q * 4 + 2] = (short)__bfloat16_as_ushort(__float2bfloat16(v.z));
                As[row * 32 + koff + q * 4 + 3] = (short)__bfloat16_as_ushort(__float2bfloat16(v.w));
            }
        }
        {   // B tile: thread -> row tid>>2, k-offset (tid&3)*8 (strided src)
            const int n = bn_row, koff = (tid & 3) * 8;
#pragma unroll
            for (int j = 0; j < 8; ++j) {
                const float v = Bsrc[(size_t)(k0 + koff + j) * ldb + n0 + n] * bscale;
                Bs[n * 32 + koff + j] = (short)__bfloat16_as_ushort(__float2bfloat16(v));
            }
        }
        __syncthreads();

        bf16x8 af[4], bfr[2];
#pragma unroll
        for (int m = 0; m < 4; ++m)
            af[m] = *(const bf16x8*)&As[(wr * 64 + m * 16 + lr) * 32 + lk];
#pragma unroll
        for (int n = 0; n < 2; ++n)
            bfr[n] = *(const bf16x8*)&Bs[(wc * 32 + n * 16 + lr) * 32 + lk];
#pragma unroll
        for (int m = 0; m < 4; ++m)
#pragma unroll
            for (int n = 0; n < 2; ++n)
                acc[m][n] = __builtin_amdgcn_mfma_f32_16x16x32_bf16(
                    af[m], bfr[n], acc[m][n], 0, 0, 0);
    }

    const int mBase = m0 + wr * 64, nBase = n0 + wc * 32;
#pragma unroll
    for (int m = 0; m < 4; ++m) {
#pragma unroll
        for (int j = 0; j < 4; ++j) {
            const int row = mBase + m * 16 + (ln >> 4) * 4 + j;
#pragma unroll
            for (int n = 0; n < 2; ++n) {
                const int col = nBase + n * 16 + lr;
                Ch[(size_t)row * ldc + col] = __float2bfloat16(acc[m][n][j]);
            }
        }
    }
}

// ---------------------------------------------------------------------------
// D1: Wfuse/Wbig GEMMs (fp32 sources) + prep (Wc/bc, zbias, hsT).
//  [0,136):     Wfuse[e][c] = sum_d ip[e][d]*pi[d][c]      (17 x 8 tiles)
//  [136,200):   Wbig[c][d]  = sum_o po[c][o]*op[o][d]*nw[d] (4 x 16 tiles)
//  [200,328):   Wc[h][c] fp32 (+bc)
//  [328,872):   zbias[e] = pib . ip[e]
//  [872,2920):  hsT[v][c] = bf16(hs[c][v])
// ---------------------------------------------------------------------------
#define NB_D1  2920

__global__ __launch_bounds__(256) void d1_kernel(
    const float* __restrict__ pi, const float* __restrict__ po,
    const float* __restrict__ op, const float* __restrict__ ip,
    const float* __restrict__ nw, const float* __restrict__ pib,
    const float* __restrict__ hs,
    bf16* __restrict__ Wfuse, bf16* __restrict__ Wbig, bf16* __restrict__ hsT,
    float* __restrict__ Wc, float* __restrict__ bc, float* __restrict__ zbias)
{
    __shared__ __align__(16) char smemraw[16384];
    const int b = blockIdx.x, tid = threadIdx.x;

    if (b < 136) {
        short* As = (short*)smemraw;
        short* Bs = As + 4096;
        gemm_f32t<false>(As, Bs, ip, pi, nullptr, Wfuse,
                         b >> 3, b & 7, DMODEL, DMODEL, DMODEL, DMODEL);
    } else if (b < 200) {
        short* As = (short*)smemraw;
        short* Bs = As + 4096;
        const int u = b - 136;
        gemm_f32t<true>(As, Bs, po, op, nw, Wbig,
                        u & 3, u >> 2, DMODEL, DMODEL, DINNER, DINNER);
    } else if (b < 328) {
        float* smem = (float*)smemraw;
        const int b2 = b - 200;
        const int h = b2 >> 3, c0 = (b2 & 7) * 64;
        const int w = tid >> 6, l = tid & 63;
        const float* wdt = ip + (size_t)(DTOFF + h) * DMODEL;
        float acc = 0.f;
#pragma unroll 8
        for (int i = 0; i < 128; ++i) {
            const int d = w * 128 + i;
            acc = fmaf(wdt[d], pi[(size_t)d * DMODEL + c0 + l], acc);
        }
        smem[w * 64 + l] = acc;
        __syncthreads();
        if (tid < 64)
            Wc[(size_t)h * DMODEL + c0 + tid] =
                smem[tid] + smem[64 + tid] + smem[128 + tid] + smem[192 + tid];
        if ((b2 & 7) == 0) {
            float p = pib[tid] * wdt[tid] + pib[tid + 256] * wdt[tid + 256];
#pragma unroll
            for (int off = 32; off >= 1; off >>= 1) p += __shfl_xor(p, off);
            if ((tid & 63) == 0) smem[300 + (tid >> 6)] = p;
            __syncthreads();
            if (tid == 0)
                bc[h] = smem[300] + smem[301] + smem[302] + smem[303];
        }
    } else if (b < 872) {
        const int e = (b - 328) * 4 + (tid >> 6);
        const int l = tid & 63;
        const float* row = ip + (size_t)e * DMODEL;
        float acc = 0.f;
#pragma unroll
        for (int i = 0; i < 8; ++i)
            acc = fmaf(pib[l + i * 64], row[l + i * 64], acc);
#pragma unroll
        for (int off = 32; off >= 1; off >>= 1) acc += __shfl_xor(acc, off);
        if (l == 0) zbias[e] = acc;
    } else {
        float* smem = (float*)smemraw;
        const int tb = b - 872;
        const int v0 = (tb & 127) * 32, c0 = (tb >> 7) * 32;
        const int tx = tid & 31, ty = tid >> 5;
#pragma unroll
        for (int i = 0; i < 4; ++i)
            smem[(ty + 8 * i) * 33 + tx] =
                hs[(size_t)(c0 + ty + 8 * i) * TOK + v0 + tx];
        __syncthreads();
#pragma unroll
        for (int i = 0; i < 4; ++i)
            hsT[(size_t)(v0 + ty + 8 * i) * DMODEL + c0 + tx] =
                __float2bfloat16(smem[tx * 33 + ty + 8 * i]);
    }
}

// ---------------------------------------------------------------------------
// D2: zb GEMM + dt, INTERLEAVED for co-residency (MFMA blocks || VALU blocks).
//  b < 1088: even -> GEMM tile b/2 (544 total); odd -> dt unit b/2.
//  b >= 1088: dt unit 544 + (b-1088).   (dt units: 1024 total)
//  GEMM: zb[v][e] = hsT[v][:] . Wfuse[e][:] + zbias[e]
//  dt:   wave w -> token v = unit*4+w, all 16 heads (fp32 acc)
// ---------------------------------------------------------------------------
__global__ __launch_bounds__(256) void d2_kernel(
    const bf16* __restrict__ hsT, const bf16* __restrict__ Wfuse,
    const float* __restrict__ zbias, const float* __restrict__ Wc,
    const float* __restrict__ bc,
    bf16* __restrict__ zb, float* __restrict__ dtf)
{
    __shared__ __align__(16) char smemraw[16384];
    const int b = blockIdx.x;

    int gemm_u = -1, dt_u = -1;
    if (b < 1088) {
        if ((b & 1) == 0) gemm_u = b >> 1;
        else              dt_u   = b >> 1;
    } else {
        dt_u = 544 + (b - 1088);
    }

    if (gemm_u >= 0) {
        short* As = (short*)smemraw;
        short* Bs = As + 4096;
        gemm_core<4>(As, Bs, hsT, Wfuse, zbias, zb,
                     gemm_u & 31, gemm_u >> 5, DMODEL, DMODEL, DMODEL, ZLD, ZLD);
    } else {
        const int tid = threadIdx.x;
        const int w = tid >> 6, l = tid & 63;
        const int v = dt_u * 4 + w;
        const bf16x8 hv = *(const bf16x8*)(hsT + (size_t)v * DMODEL + l * 8);
        float hf[8];
#pragma unroll
        for (int j = 0; j < 8; ++j) {
            const unsigned int bits = ((unsigned int)(unsigned short)hv[j]) << 16;
            hf[j] = __uint_as_float(bits);
        }
#pragma unroll
        for (int h = 0; h < 16; ++h) {
            const float4* wr_ = (const float4*)(Wc + (size_t)h * DMODEL);
            const float4 w0 = wr_[l * 2], w1 = wr_[l * 2 + 1];
            float dot = hf[0] * w0.x + hf[1] * w0.y + hf[2] * w0.z + hf[3] * w0.w
                      + hf[4] * w1.x + hf[5] * w1.y + hf[6] * w1.z + hf[7] * w1.w;
#pragma unroll
            for (int off = 32; off >= 1; off >>= 1) dot += __shfl_xor(dot, off);
            if (l == 0) dtf[(size_t)v * 16 + h] = dot + bc[h];
        }
    }
}

// ---------------------------------------------------------------------------
// D3: fused conv + SSD + D-skip + z-gating -> gb (bf16) + partial sumsq.
// Grid (n, hq): 256 x 4 blocks, 256 threads = 4 waves; wave w = head hq*4+w.
// ---------------------------------------------------------------------------
__global__ __launch_bounds__(256) void ssd_kernel(
    const bf16* __restrict__ zb, const float* __restrict__ dtf,
    const float* __restrict__ conv_w, const float* __restrict__ conv_b,
    const float* __restrict__ dt_bias, const float* __restrict__ A_log,
    const float* __restrict__ Dp,
    bf16* __restrict__ gb, float* __restrict__ part)
{
    const int n = blockIdx.x, hq = blockIdx.y;
    const int tid = threadIdx.x;
    const int w = tid >> 6, p = tid & 63;
    const int h = hq * 4 + w;
    const int ch = hq * 256 + tid;

    __shared__ float Bsh[16][68];
    __shared__ float Csh[16][68];
    __shared__ float Gsh[16][16];
    __shared__ float Msh[4][256];
    __shared__ float red4[16][4];

    float ld[16];
#pragma unroll
    for (int t = 0; t < 16; ++t)
        ld[t] = __bfloat162float(zb[(size_t)(t * 256 + n) * ZLD + 1024 + ch]);

    const float cw0 = conv_w[ch * 4 + 0], cw1 = conv_w[ch * 4 + 1],
                cw2 = conv_w[ch * 4 + 2], cw3 = conv_w[ch * 4 + 3];
    const float cb = conv_b[ch];
    float xs[16];
#pragma unroll
    for (int t = 0; t < 16; ++t) {
        float a = fmaf(ld[t], cw3, cb);
        if (t >= 1) a = fmaf(ld[t - 1], cw2, a);
        if (t >= 2) a = fmaf(ld[t - 2], cw1, a);
        if (t >= 3) a = fmaf(ld[t - 3], cw0, a);
        xs[t] = a / (1.f + __expf(-a));
    }

    if (tid < 128) {
        const int cc = 1024 + tid;
        const float dw0 = conv_w[cc * 4 + 0], dw1 = conv_w[cc * 4 + 1],
                    dw2 = conv_w[cc * 4 + 2], dw3 = conv_w[cc * 4 + 3];
        const float db = conv_b[cc];
        float q0 = 0.f, q1 = 0.f, q2 = 0.f;
#pragma unroll
        for (int t = 0; t < 16; ++t) {
            const float cur =
                __bfloat162float(zb[(size_t)(t * 256 + n) * ZLD + 2048 + tid]);
            float a = fmaf(cur, dw3, db);
            a = fmaf(q2, dw2, a);
            a = fmaf(q1, dw1, a);
            a = fmaf(q0, dw0, a);
            const float val = a / (1.f + __expf(-a));
            if (tid < 64) Bsh[t][tid] = val; else Csh[t][tid - 64] = val;
            q0 = q1; q1 = q2; q2 = cur;
        }
    }

    const float a_h = -__expf(A_log[h]);
    float dtv_l = 0.f;
    if (p < 16) {
        const float raw = dtf[(size_t)(p * 256 + n) * 16 + h] + dt_bias[h];
        dtv_l = (raw > 20.f) ? raw : log1pf(__expf(raw));
    }
    float cum_l = dtv_l;
#pragma unroll
    for (int off = 1; off < 16; off <<= 1) {
        const float tmp = __shfl_up(cum_l, off);
        if (p >= off) cum_l += tmp;
    }
    __syncthreads();

    {
        const int t = tid >> 4, s = tid & 15;
        float acc = 0.f;
#pragma unroll
        for (int k = 0; k < 64; ++k)
            acc = fmaf(Csh[t][k], Bsh[s][k], acc);
        Gsh[t][s] = acc;
    }
    __syncthreads();

    float dtv_all[16], cum_all[16];
#pragma unroll
    for (int t = 0; t < 16; ++t) {
        dtv_all[t] = __shfl(dtv_l, t);
        cum_all[t] = __shfl(cum_l, t);
    }
#pragma unroll
    for (int q = 0; q < 4; ++q) {
        const int idx = p * 4 + q;
        const int t = idx >> 4, s = idx & 15;
        float m = 0.f;
        if (s <= t)
            m = __expf(a_h * (cum_all[t] - cum_all[s])) * Gsh[t][s] * dtv_all[s];
        Msh[w][idx] = m;
    }

    float zl[16];
#pragma unroll
    for (int t = 0; t < 16; ++t)
        zl[t] = __bfloat162float(zb[(size_t)(t * 256 + n) * ZLD + ch]);

    const float Dh = Dp[h];
    float g[16];
#pragma unroll
    for (int t = 0; t < 16; ++t) {
        float y = 0.f;
#pragma unroll
        for (int s = 0; s <= t; ++s)
            y = fmaf(Msh[w][t * 16 + s], xs[s], y);
        y = fmaf(Dh, xs[t], y);
        g[t] = y * (zl[t] / (1.f + __expf(-zl[t])));
    }

#pragma unroll
    for (int t = 0; t < 16; ++t) {
        float ss = g[t] * g[t];
#pragma unroll
        for (int off = 32; off >= 1; off >>= 1) ss += __shfl_xor(ss, off);
        if (p == 0) red4[t][w] = ss;
        gb[(size_t)(t * 256 + n) * DINNER + ch] = __float2bfloat16(g[t]);
    }
    __syncthreads();
    if (tid < 16)
        part[(size_t)(tid * 256 + n) * 4 + hq] =
            red4[tid][0] + red4[tid][1] + red4[tid][2] + red4[tid][3];
}

// ---------------------------------------------------------------------------
// D4: out[c][v] = rsqrt(mean part[v] + eps) * (Wbig[c][:] . gb[v][:]) + pob[c]
// fp32 out, row-major = out layout. Tile 128 x 32, grid (4,128) = 512 blocks
// (2 blocks/CU for barrier-latency hiding; shape validated in r15 mega).
// ---------------------------------------------------------------------------
__global__ __launch_bounds__(256) void k67_gemm(
    const bf16* __restrict__ A, const bf16* __restrict__ B,
    const float* __restrict__ bias, const float* __restrict__ rs,
    float* __restrict__ Cf)
{
    __shared__ short As[128 * 32];
    __shared__ short Bs[32 * 32];

    const int tid = threadIdx.x;
    const int wv = tid >> 6, ln = tid & 63;
    const int m0 = blockIdx.x * 128, n0 = blockIdx.y * 32;
    const int wr = wv >> 1, wc = wv & 1;
    const int lr = ln & 15, lk = (ln >> 4) * 8;

    f32x4 acc[4];
#pragma unroll
    for (int m = 0; m < 4; ++m) acc[m] = (f32x4){0.f, 0.f, 0.f, 0.f};

    for (int k0 = 0; k0 < DINNER; k0 += 32) {
        __syncthreads();
#pragma unroll
        for (int r = 0; r < 2; ++r) {
            const int ofs = r * 4096 + tid * 16;
            const int row = ofs >> 6, ke = (ofs & 63) >> 1;
            gload_lds16(A + (size_t)(m0 + row) * DINNER + k0 + ke, (char*)As + ofs);
        }
        if (tid < 128) {
            const int ofs = tid * 16;
            const int row = ofs >> 6, ke = (ofs & 63) >> 1;
            gload_lds16(B + (size_t)(n0 + row) * DINNER + k0 + ke, (char*)Bs + ofs);
        }
        __syncthreads();

        bf16x8 af[4], bfr;
#pragma unroll
        for (int m = 0; m < 4; ++m)
            af[m] = *(const bf16x8*)&As[(wr * 64 + m * 16 + lr) * 32 + lk];
        bfr = *(const bf16x8*)&Bs[(wc * 16 + lr) * 32 + lk];
#pragma unroll
        for (int m = 0; m < 4; ++m)
            acc[m] = __builtin_amdgcn_mfma_f32_16x16x32_bf16(af[m], bfr, acc[m], 0, 0, 0);
    }

    const int mBase = m0 + wr * 64;
    const int col = n0 + wc * 16 + lr;
    const float4 pv = *(const float4*)(rs + (size_t)col * 4);
    const float sc = rsqrtf((pv.x + pv.y + pv.z + pv.w) * (1.f / 1024.f) + 1e-5f);
#pragma unroll
    for (int m = 0; m < 4; ++m) {
#pragma unroll
        for (int j = 0; j < 4; ++j) {
            const int row = mBase + m * 16 + (ln >> 4) * 4 + j;
            Cf[(size_t)row * TOK + col] = acc[m][j] * sc + bias[row];
        }
    }
}

// ---------------------------------------------------------------------------
extern "C" void kernel_launch(void* const* d_in, const int* in_sizes, int n_in,
                              void* d_out, int out_size, void* d_ws, size_t ws_size,
                              hipStream_t stream) {
    const float* hs         = (const float*)d_in[0];
    const float* proj_in_w  = (const float*)d_in[1];
    const float* proj_in_b  = (const float*)d_in[2];
    const float* proj_out_w = (const float*)d_in[3];
    const float* proj_out_b = (const float*)d_in[4];
    const float* in_proj_w  = (const float*)d_in[5];
    const float* conv_w     = (const float*)d_in[6];
    const float* conv_b     = (const float*)d_in[7];
    const float* dt_bias    = (const float*)d_in[8];
    const float* A_log      = (const float*)d_in[9];
    const float* Dp         = (const float*)d_in[10];
    const float* norm_w     = (const float*)d_in[11];
    const float* out_proj_w = (const float*)d_in[12];
    float* out = (float*)d_out;

    // workspace layout (fp32 first, then bf16)
    float* ws    = (float*)d_ws;
    float* dtf   = ws;                                  // 4096*16 f32
    float* part  = dtf + (size_t)TOK * 16;              // 4096*4  f32
    float* Wc    = part + (size_t)TOK * 4;              // 16*512  f32
    float* bc    = Wc + 16 * DMODEL;                    // 16      f32
    float* zbias = bc + 16;                             // 2176    f32
    bf16*  hsT   = (bf16*)(zbias + ZLD);                // 4096*512
    bf16*  zb    = hsT + (size_t)TOK * DMODEL;          // 4096*2176
    bf16*  gb    = zb + (size_t)TOK * ZLD;              // 4096*1024
    bf16*  Wfuse = gb + (size_t)TOK * DINNER;           // 2176*512
    bf16*  Wbig  = Wfuse + (size_t)ZLD * DMODEL;        // 512*1024

    // D1: W-product GEMMs (fp32 sources) + Wc/bc/zbias + hsT transpose
    d1_kernel<<<NB_D1, 256, 0, stream>>>(
        proj_in_w, proj_out_w, out_proj_w, in_proj_w, norm_w, proj_in_b, hs,
        Wfuse, Wbig, hsT, Wc, bc, zbias);

    // D2: zb = hsT . Wfuse^T + zbias (bf16)  and  dtf = hsT . Wc^T + bc (fp32)
    d2_kernel<<<544 + 1024, 256, 0, stream>>>(
        hsT, Wfuse, zbias, Wc, bc, zb, dtf);

    // D3: fused conv + SSD + gate -> gb + part
    ssd_kernel<<<dim3(NSEQ, 4), 256, 0, stream>>>(
        zb, dtf, conv_w, conv_b, dt_bias, A_log, Dp, gb, part);

    // D4: out = colscale(part) * (Wbig . gb^T) + pob   (512 blocks, 2/CU)
    k67_gemm<<<dim3(4, 128), 256, 0, stream>>>(
        Wbig, gb, proj_out_b, part, out);
}

// Round 18
// 101.541 us; speedup vs baseline: 1.0124x; 1.0124x over previous
//
#include <hip/hip_runtime.h>
#include <hip/hip_bf16.h>
#include <math.h>

// Problem constants
#define TT       16
#define NSEQ     256
#define TOK      4096
#define DMODEL   512
#define DINNER   1024
#define DSTATE   64
#define NHEADS   16
#define HEADDIM  64
#define DINPROJ  2192
#define DTOFF    2176
#define ZLD      2176    // zb row stride (z:0..1023, x:1024..2047, BC:2048..2175)

using bf16x8 = __attribute__((ext_vector_type(8))) short;
using f32x4  = __attribute__((ext_vector_type(4))) float;
typedef __hip_bfloat16 bf16;

__device__ __forceinline__ void gload_lds16(const void* g, void* l) {
    __builtin_amdgcn_global_load_lds(
        (const __attribute__((address_space(1))) unsigned int*)g,
        (__attribute__((address_space(3))) unsigned int*)l,
        16, 0, 0);
}

// ---------------------------------------------------------------------------
// GEMM core (bf16 sources via global_load_lds):
// C[M][N] = A[M][K]*B[N][K]^T (+ bias[col]), bf16 out.
// Tile 128 x (NFRAG*32), BK=32, 256 threads (4 waves, 2x2 wave grid).
// ---------------------------------------------------------------------------
template<int NFRAG>
__device__ __forceinline__ void gemm_core(
    short* As, short* Bs,
    const bf16* __restrict__ A, const bf16* __restrict__ B,
    const float* __restrict__ bias, bf16* __restrict__ Ch,
    int bm, int bn, int K, int lda, int ldb, int ldc, int Nreal)
{
    constexpr int BN = NFRAG * 32;
    const int tid = threadIdx.x;
    const int wv = tid >> 6, ln = tid & 63;
    const int m0 = bm * 128, n0 = bn * BN;
    const int wr = wv >> 1, wc = wv & 1;
    const int lr = ln & 15, lk = (ln >> 4) * 8;

    f32x4 acc[4][NFRAG];
#pragma unroll
    for (int m = 0; m < 4; ++m)
#pragma unroll
        for (int n = 0; n < NFRAG; ++n) acc[m][n] = (f32x4){0.f, 0.f, 0.f, 0.f};

    for (int k0 = 0; k0 < K; k0 += 32) {
        __syncthreads();
#pragma unroll
        for (int r = 0; r < 2; ++r) {
            const int ofs = r * 4096 + tid * 16;
            const int row = ofs >> 6, ke = (ofs & 63) >> 1;
            gload_lds16(A + (size_t)(m0 + row) * lda + k0 + ke, (char*)As + ofs);
        }
#pragma unroll
        for (int r = 0; r < NFRAG / 2; ++r) {
            const int ofs = r * 4096 + tid * 16;
            const int row = ofs >> 6, ke = (ofs & 63) >> 1;
            gload_lds16(B + (size_t)(n0 + row) * ldb + k0 + ke, (char*)Bs + ofs);
        }
        __syncthreads();

        bf16x8 af[4], bfr[NFRAG];
#pragma unroll
        for (int m = 0; m < 4; ++m)
            af[m] = *(const bf16x8*)&As[(wr * 64 + m * 16 + lr) * 32 + lk];
#pragma unroll
        for (int n = 0; n < NFRAG; ++n)
            bfr[n] = *(const bf16x8*)&Bs[(wc * (BN / 2) + n * 16 + lr) * 32 + lk];
#pragma unroll
        for (int m = 0; m < 4; ++m)
#pragma unroll
            for (int n = 0; n < NFRAG; ++n)
                acc[m][n] = __builtin_amdgcn_mfma_f32_16x16x32_bf16(
                    af[m], bfr[n], acc[m][n], 0, 0, 0);
    }

    const int mBase = m0 + wr * 64, nBase = n0 + wc * (BN / 2);
    float cbv[NFRAG];
#pragma unroll
    for (int n = 0; n < NFRAG; ++n) {
        const int col = nBase + n * 16 + lr;
        cbv[n] = (bias != nullptr && col < Nreal) ? bias[col] : 0.f;
    }
#pragma unroll
    for (int m = 0; m < 4; ++m) {
#pragma unroll
        for (int j = 0; j < 4; ++j) {
            const int row = mBase + m * 16 + (ln >> 4) * 4 + j;
#pragma unroll
            for (int n = 0; n < NFRAG; ++n) {
                const int col = nBase + n * 16 + lr;
                if (col < Nreal)
                    Ch[(size_t)row * ldc + col] =
                        __float2bfloat16(acc[m][n][j] + cbv[n]);
            }
        }
    }
}

// ---------------------------------------------------------------------------
// GEMM core with fp32 sources (register-staged, converted to bf16 in-flight):
//   A(m,k) = A[(m0+m)*lda + k]                         (fp32 row-major)
//   B(n,k) = Bsrc[k*ldb + n0+n] * (SCALE? scale[n0+n]) (fp32 TRANSPOSED src)
// C bf16 out, no bias. Tile 128 x 64 (NFRAG=2), BK=32.
// ---------------------------------------------------------------------------
template<bool SCALE>
__device__ __forceinline__ void gemm_f32t(
    short* As, short* Bs,
    const float* __restrict__ A, const float* __restrict__ Bsrc,
    const float* __restrict__ scale, bf16* __restrict__ Ch,
    int bm, int bn, int K, int lda, int ldb, int ldc)
{
    const int tid = threadIdx.x;
    const int wv = tid >> 6, ln = tid & 63;
    const int m0 = bm * 128, n0 = bn * 64;
    const int wr = wv >> 1, wc = wv & 1;
    const int lr = ln & 15, lk = (ln >> 4) * 8;

    const int bn_row = tid >> 2;
    const float bscale = SCALE ? scale[n0 + bn_row] : 1.f;

    f32x4 acc[4][2];
#pragma unroll
    for (int m = 0; m < 4; ++m)
#pragma unroll
        for (int n = 0; n < 2; ++n) acc[m][n] = (f32x4){0.f, 0.f, 0.f, 0.f};

    for (int k0 = 0; k0 < K; k0 += 32) {
        __syncthreads();
        {   // A tile: thread -> row tid>>1, k-offset (tid&1)*16 (4x float4)
            const int row = tid >> 1, koff = (tid & 1) * 16;
            const float* src = A + (size_t)(m0 + row) * lda + k0 + koff;
#pragma unroll
            for (int q = 0; q < 4; ++q) {
                const float4 v = *(const float4*)(src + q * 4);
                As[row * 32 + koff + q * 4 + 0] = (short)__bfloat16_as_ushort(__float2bfloat16(v.x));
                As[row * 32 + koff + q * 4 + 1] = (short)__bfloat16_as_ushort(__float2bfloat16(v.y));
                As[row * 32 + koff + q * 4 + 2] = (short)__bfloat16_as_ushort(__float2bfloat16(v.z));
                As[row * 32 + koff + q * 4 + 3] = (short)__bfloat16_as_ushort(__float2bfloat16(v.w));
            }
        }
        {   // B tile: thread -> row tid>>2, k-offset (tid&3)*8 (strided src)
            const int n = bn_row, koff = (tid & 3) * 8;
#pragma unroll
            for (int j = 0; j < 8; ++j) {
                const float v = Bsrc[(size_t)(k0 + koff + j) * ldb + n0 + n] * bscale;
                Bs[n * 32 + koff + j] = (short)__bfloat16_as_ushort(__float2bfloat16(v));
            }
        }
        __syncthreads();

        bf16x8 af[4], bfr[2];
#pragma unroll
        for (int m = 0; m < 4; ++m)
            af[m] = *(const bf16x8*)&As[(wr * 64 + m * 16 + lr) * 32 + lk];
#pragma unroll
        for (int n = 0; n < 2; ++n)
            bfr[n] = *(const bf16x8*)&Bs[(wc * 32 + n * 16 + lr) * 32 + lk];
#pragma unroll
        for (int m = 0; m < 4; ++m)
#pragma unroll
            for (int n = 0; n < 2; ++n)
                acc[m][n] = __builtin_amdgcn_mfma_f32_16x16x32_bf16(
                    af[m], bfr[n], acc[m][n], 0, 0, 0);
    }

    const int mBase = m0 + wr * 64, nBase = n0 + wc * 32;
#pragma unroll
    for (int m = 0; m < 4; ++m) {
#pragma unroll
        for (int j = 0; j < 4; ++j) {
            const int row = mBase + m * 16 + (ln >> 4) * 4 + j;
#pragma unroll
            for (int n = 0; n < 2; ++n) {
                const int col = nBase + n * 16 + lr;
                Ch[(size_t)row * ldc + col] = __float2bfloat16(acc[m][n][j]);
            }
        }
    }
}

// ---------------------------------------------------------------------------
// D1: Wfuse/Wbig GEMMs (fp32 sources) + prep (Wc/bc, zbias, hsT).
//  [0,136):     Wfuse[e][c] = sum_d ip[e][d]*pi[d][c]      (17 x 8 tiles)
//  [136,200):   Wbig[c][d]  = sum_o po[c][o]*op[o][d]*nw[d] (4 x 16 tiles)
//  [200,328):   Wc[h][c] fp32 (+bc)
//  [328,872):   zbias[e] = pib . ip[e]
//  [872,2920):  hsT[v][c] = bf16(hs[c][v])
// ---------------------------------------------------------------------------
#define NB_D1  2920

__global__ __launch_bounds__(256) void d1_kernel(
    const float* __restrict__ pi, const float* __restrict__ po,
    const float* __restrict__ op, const float* __restrict__ ip,
    const float* __restrict__ nw, const float* __restrict__ pib,
    const float* __restrict__ hs,
    bf16* __restrict__ Wfuse, bf16* __restrict__ Wbig, bf16* __restrict__ hsT,
    float* __restrict__ Wc, float* __restrict__ bc, float* __restrict__ zbias)
{
    __shared__ __align__(16) char smemraw[16384];
    const int b = blockIdx.x, tid = threadIdx.x;

    if (b < 136) {
        short* As = (short*)smemraw;
        short* Bs = As + 4096;
        gemm_f32t<false>(As, Bs, ip, pi, nullptr, Wfuse,
                         b >> 3, b & 7, DMODEL, DMODEL, DMODEL, DMODEL);
    } else if (b < 200) {
        short* As = (short*)smemraw;
        short* Bs = As + 4096;
        const int u = b - 136;
        gemm_f32t<true>(As, Bs, po, op, nw, Wbig,
                        u & 3, u >> 2, DMODEL, DMODEL, DINNER, DINNER);
    } else if (b < 328) {
        float* smem = (float*)smemraw;
        const int b2 = b - 200;
        const int h = b2 >> 3, c0 = (b2 & 7) * 64;
        const int w = tid >> 6, l = tid & 63;
        const float* wdt = ip + (size_t)(DTOFF + h) * DMODEL;
        float acc = 0.f;
#pragma unroll 8
        for (int i = 0; i < 128; ++i) {
            const int d = w * 128 + i;
            acc = fmaf(wdt[d], pi[(size_t)d * DMODEL + c0 + l], acc);
        }
        smem[w * 64 + l] = acc;
        __syncthreads();
        if (tid < 64)
            Wc[(size_t)h * DMODEL + c0 + tid] =
                smem[tid] + smem[64 + tid] + smem[128 + tid] + smem[192 + tid];
        if ((b2 & 7) == 0) {
            float p = pib[tid] * wdt[tid] + pib[tid + 256] * wdt[tid + 256];
#pragma unroll
            for (int off = 32; off >= 1; off >>= 1) p += __shfl_xor(p, off);
            if ((tid & 63) == 0) smem[300 + (tid >> 6)] = p;
            __syncthreads();
            if (tid == 0)
                bc[h] = smem[300] + smem[301] + smem[302] + smem[303];
        }
    } else if (b < 872) {
        const int e = (b - 328) * 4 + (tid >> 6);
        const int l = tid & 63;
        const float* row = ip + (size_t)e * DMODEL;
        float acc = 0.f;
#pragma unroll
        for (int i = 0; i < 8; ++i)
            acc = fmaf(pib[l + i * 64], row[l + i * 64], acc);
#pragma unroll
        for (int off = 32; off >= 1; off >>= 1) acc += __shfl_xor(acc, off);
        if (l == 0) zbias[e] = acc;
    } else {
        float* smem = (float*)smemraw;
        const int tb = b - 872;
        const int v0 = (tb & 127) * 32, c0 = (tb >> 7) * 32;
        const int tx = tid & 31, ty = tid >> 5;
#pragma unroll
        for (int i = 0; i < 4; ++i)
            smem[(ty + 8 * i) * 33 + tx] =
                hs[(size_t)(c0 + ty + 8 * i) * TOK + v0 + tx];
        __syncthreads();
#pragma unroll
        for (int i = 0; i < 4; ++i)
            hsT[(size_t)(v0 + ty + 8 * i) * DMODEL + c0 + tx] =
                __float2bfloat16(smem[tx * 33 + ty + 8 * i]);
    }
}

// ---------------------------------------------------------------------------
// D2: dt blocks FIRST (light, latency-bound -> fill CUs, overlap with GEMM),
// then the zb GEMM blocks.
//  [0,1024):    dt: wave w -> token v = b*4+w, all 16 heads (fp32 acc)
//  [1024,1568): zb[v][e] = hsT[v][:] . Wfuse[e][:] + zbias[e]  (tile b-1024)
// ---------------------------------------------------------------------------
__global__ __launch_bounds__(256) void d2_kernel(
    const bf16* __restrict__ hsT, const bf16* __restrict__ Wfuse,
    const float* __restrict__ zbias, const float* __restrict__ Wc,
    const float* __restrict__ bc,
    bf16* __restrict__ zb, float* __restrict__ dtf)
{
    __shared__ __align__(16) char smemraw[16384];
    const int b = blockIdx.x;

    if (b >= 1024) {
        const int u = b - 1024;
        short* As = (short*)smemraw;
        short* Bs = As + 4096;
        gemm_core<4>(As, Bs, hsT, Wfuse, zbias, zb,
                     u & 31, u >> 5, DMODEL, DMODEL, DMODEL, ZLD, ZLD);
    } else {
        const int tid = threadIdx.x;
        const int w = tid >> 6, l = tid & 63;
        const int v = b * 4 + w;
        const bf16x8 hv = *(const bf16x8*)(hsT + (size_t)v * DMODEL + l * 8);
        float hf[8];
#pragma unroll
        for (int j = 0; j < 8; ++j) {
            const unsigned int bits = ((unsigned int)(unsigned short)hv[j]) << 16;
            hf[j] = __uint_as_float(bits);
        }
#pragma unroll
        for (int h = 0; h < 16; ++h) {
            const float4* wr_ = (const float4*)(Wc + (size_t)h * DMODEL);
            const float4 w0 = wr_[l * 2], w1 = wr_[l * 2 + 1];
            float dot = hf[0] * w0.x + hf[1] * w0.y + hf[2] * w0.z + hf[3] * w0.w
                      + hf[4] * w1.x + hf[5] * w1.y + hf[6] * w1.z + hf[7] * w1.w;
#pragma unroll
            for (int off = 32; off >= 1; off >>= 1) dot += __shfl_xor(dot, off);
            if (l == 0) dtf[(size_t)v * 16 + h] = dot + bc[h];
        }
    }
}

// ---------------------------------------------------------------------------
// D3: fused conv + SSD + D-skip + z-gating -> gb (bf16) + partial sumsq.
// Grid (n, hq): 256 x 4 blocks, 256 threads = 4 waves; wave w = head hq*4+w.
// ---------------------------------------------------------------------------
__global__ __launch_bounds__(256) void ssd_kernel(
    const bf16* __restrict__ zb, const float* __restrict__ dtf,
    const float* __restrict__ conv_w, const float* __restrict__ conv_b,
    const float* __restrict__ dt_bias, const float* __restrict__ A_log,
    const float* __restrict__ Dp,
    bf16* __restrict__ gb, float* __restrict__ part)
{
    const int n = blockIdx.x, hq = blockIdx.y;
    const int tid = threadIdx.x;
    const int w = tid >> 6, p = tid & 63;
    const int h = hq * 4 + w;
    const int ch = hq * 256 + tid;

    __shared__ float Bsh[16][68];
    __shared__ float Csh[16][68];
    __shared__ float Gsh[16][16];
    __shared__ float Msh[4][256];
    __shared__ float red4[16][4];

    float ld[16];
#pragma unroll
    for (int t = 0; t < 16; ++t)
        ld[t] = __bfloat162float(zb[(size_t)(t * 256 + n) * ZLD + 1024 + ch]);

    const float cw0 = conv_w[ch * 4 + 0], cw1 = conv_w[ch * 4 + 1],
                cw2 = conv_w[ch * 4 + 2], cw3 = conv_w[ch * 4 + 3];
    const float cb = conv_b[ch];
    float xs[16];
#pragma unroll
    for (int t = 0; t < 16; ++t) {
        float a = fmaf(ld[t], cw3, cb);
        if (t >= 1) a = fmaf(ld[t - 1], cw2, a);
        if (t >= 2) a = fmaf(ld[t - 2], cw1, a);
        if (t >= 3) a = fmaf(ld[t - 3], cw0, a);
        xs[t] = a / (1.f + __expf(-a));
    }

    if (tid < 128) {
        const int cc = 1024 + tid;
        const float dw0 = conv_w[cc * 4 + 0], dw1 = conv_w[cc * 4 + 1],
                    dw2 = conv_w[cc * 4 + 2], dw3 = conv_w[cc * 4 + 3];
        const float db = conv_b[cc];
        float q0 = 0.f, q1 = 0.f, q2 = 0.f;
#pragma unroll
        for (int t = 0; t < 16; ++t) {
            const float cur =
                __bfloat162float(zb[(size_t)(t * 256 + n) * ZLD + 2048 + tid]);
            float a = fmaf(cur, dw3, db);
            a = fmaf(q2, dw2, a);
            a = fmaf(q1, dw1, a);
            a = fmaf(q0, dw0, a);
            const float val = a / (1.f + __expf(-a));
            if (tid < 64) Bsh[t][tid] = val; else Csh[t][tid - 64] = val;
            q0 = q1; q1 = q2; q2 = cur;
        }
    }

    const float a_h = -__expf(A_log[h]);
    float dtv_l = 0.f;
    if (p < 16) {
        const float raw = dtf[(size_t)(p * 256 + n) * 16 + h] + dt_bias[h];
        dtv_l = (raw > 20.f) ? raw : log1pf(__expf(raw));
    }
    float cum_l = dtv_l;
#pragma unroll
    for (int off = 1; off < 16; off <<= 1) {
        const float tmp = __shfl_up(cum_l, off);
        if (p >= off) cum_l += tmp;
    }
    __syncthreads();

    {
        const int t = tid >> 4, s = tid & 15;
        float acc = 0.f;
#pragma unroll
        for (int k = 0; k < 64; ++k)
            acc = fmaf(Csh[t][k], Bsh[s][k], acc);
        Gsh[t][s] = acc;
    }
    __syncthreads();

    float dtv_all[16], cum_all[16];
#pragma unroll
    for (int t = 0; t < 16; ++t) {
        dtv_all[t] = __shfl(dtv_l, t);
        cum_all[t] = __shfl(cum_l, t);
    }
#pragma unroll
    for (int q = 0; q < 4; ++q) {
        const int idx = p * 4 + q;
        const int t = idx >> 4, s = idx & 15;
        float m = 0.f;
        if (s <= t)
            m = __expf(a_h * (cum_all[t] - cum_all[s])) * Gsh[t][s] * dtv_all[s];
        Msh[w][idx] = m;
    }

    float zl[16];
#pragma unroll
    for (int t = 0; t < 16; ++t)
        zl[t] = __bfloat162float(zb[(size_t)(t * 256 + n) * ZLD + ch]);

    const float Dh = Dp[h];
    float g[16];
#pragma unroll
    for (int t = 0; t < 16; ++t) {
        float y = 0.f;
#pragma unroll
        for (int s = 0; s <= t; ++s)
            y = fmaf(Msh[w][t * 16 + s], xs[s], y);
        y = fmaf(Dh, xs[t], y);
        g[t] = y * (zl[t] / (1.f + __expf(-zl[t])));
    }

#pragma unroll
    for (int t = 0; t < 16; ++t) {
        float ss = g[t] * g[t];
#pragma unroll
        for (int off = 32; off >= 1; off >>= 1) ss += __shfl_xor(ss, off);
        if (p == 0) red4[t][w] = ss;
        gb[(size_t)(t * 256 + n) * DINNER + ch] = __float2bfloat16(g[t]);
    }
    __syncthreads();
    if (tid < 16)
        part[(size_t)(tid * 256 + n) * 4 + hq] =
            red4[tid][0] + red4[tid][1] + red4[tid][2] + red4[tid][3];
}

// ---------------------------------------------------------------------------
// D4: out[c][v] = rsqrt(mean part[v] + eps) * (Wbig[c][:] . gb[v][:]) + pob[c]
// fp32 out, row-major = out layout. Tile 128 x 64, grid (4,64) — R16 proven.
// ---------------------------------------------------------------------------
__global__ __launch_bounds__(256) void k67_gemm(
    const bf16* __restrict__ A, const bf16* __restrict__ B,
    const float* __restrict__ bias, const float* __restrict__ rs,
    float* __restrict__ Cf)
{
    __shared__ short As[128 * 32];
    __shared__ short Bs[64 * 32];

    const int tid = threadIdx.x;
    const int wv = tid >> 6, ln = tid & 63;
    const int m0 = blockIdx.x * 128, n0 = blockIdx.y * 64;
    const int wr = wv >> 1, wc = wv & 1;
    const int lr = ln & 15, lk = (ln >> 4) * 8;

    f32x4 acc[4][2];
#pragma unroll
    for (int m = 0; m < 4; ++m)
#pragma unroll
        for (int n = 0; n < 2; ++n) acc[m][n] = (f32x4){0.f, 0.f, 0.f, 0.f};

    for (int k0 = 0; k0 < DINNER; k0 += 32) {
        __syncthreads();
#pragma unroll
        for (int r = 0; r < 2; ++r) {
            const int ofs = r * 4096 + tid * 16;
            const int row = ofs >> 6, ke = (ofs & 63) >> 1;
            gload_lds16(A + (size_t)(m0 + row) * DINNER + k0 + ke, (char*)As + ofs);
        }
        {
            const int ofs = tid * 16;
            const int row = ofs >> 6, ke = (ofs & 63) >> 1;
            gload_lds16(B + (size_t)(n0 + row) * DINNER + k0 + ke, (char*)Bs + ofs);
        }
        __syncthreads();

        bf16x8 af[4], bfr[2];
#pragma unroll
        for (int m = 0; m < 4; ++m)
            af[m] = *(const bf16x8*)&As[(wr * 64 + m * 16 + lr) * 32 + lk];
#pragma unroll
        for (int n = 0; n < 2; ++n)
            bfr[n] = *(const bf16x8*)&Bs[(wc * 32 + n * 16 + lr) * 32 + lk];
#pragma unroll
        for (int m = 0; m < 4; ++m)
#pragma unroll
            for (int n = 0; n < 2; ++n)
                acc[m][n] = __builtin_amdgcn_mfma_f32_16x16x32_bf16(
                    af[m], bfr[n], acc[m][n], 0, 0, 0);
    }

    const int mBase = m0 + wr * 64, nBase = n0 + wc * 32;
    float scn[2];
#pragma unroll
    for (int n = 0; n < 2; ++n) {
        const int col = nBase + n * 16 + lr;
        const float4 pv = *(const float4*)(rs + (size_t)col * 4);
        scn[n] = rsqrtf((pv.x + pv.y + pv.z + pv.w) * (1.f / 1024.f) + 1e-5f);
    }
#pragma unroll
    for (int m = 0; m < 4; ++m) {
#pragma unroll
        for (int j = 0; j < 4; ++j) {
            const int row = mBase + m * 16 + (ln >> 4) * 4 + j;
            const float rb = bias[row];
#pragma unroll
            for (int n = 0; n < 2; ++n) {
                const int col = nBase + n * 16 + lr;
                Cf[(size_t)row * TOK + col] = acc[m][n][j] * scn[n] + rb;
            }
        }
    }
}

// ---------------------------------------------------------------------------
extern "C" void kernel_launch(void* const* d_in, const int* in_sizes, int n_in,
                              void* d_out, int out_size, void* d_ws, size_t ws_size,
                              hipStream_t stream) {
    const float* hs         = (const float*)d_in[0];
    const float* proj_in_w  = (const float*)d_in[1];
    const float* proj_in_b  = (const float*)d_in[2];
    const float* proj_out_w = (const float*)d_in[3];
    const float* proj_out_b = (const float*)d_in[4];
    const float* in_proj_w  = (const float*)d_in[5];
    const float* conv_w     = (const float*)d_in[6];
    const float* conv_b     = (const float*)d_in[7];
    const float* dt_bias    = (const float*)d_in[8];
    const float* A_log      = (const float*)d_in[9];
    const float* Dp         = (const float*)d_in[10];
    const float* norm_w     = (const float*)d_in[11];
    const float* out_proj_w = (const float*)d_in[12];
    float* out = (float*)d_out;

    // workspace layout (fp32 first, then bf16)
    float* ws    = (float*)d_ws;
    float* dtf   = ws;                                  // 4096*16 f32
    float* part  = dtf + (size_t)TOK * 16;              // 4096*4  f32
    float* Wc    = part + (size_t)TOK * 4;              // 16*512  f32
    float* bc    = Wc + 16 * DMODEL;                    // 16      f32
    float* zbias = bc + 16;                             // 2176    f32
    bf16*  hsT   = (bf16*)(zbias + ZLD);                // 4096*512
    bf16*  zb    = hsT + (size_t)TOK * DMODEL;          // 4096*2176
    bf16*  gb    = zb + (size_t)TOK * ZLD;              // 4096*1024
    bf16*  Wfuse = gb + (size_t)TOK * DINNER;           // 2176*512
    bf16*  Wbig  = Wfuse + (size_t)ZLD * DMODEL;        // 512*1024

    // D1: W-product GEMMs (fp32 sources) + Wc/bc/zbias + hsT transpose
    d1_kernel<<<NB_D1, 256, 0, stream>>>(
        proj_in_w, proj_out_w, out_proj_w, in_proj_w, norm_w, proj_in_b, hs,
        Wfuse, Wbig, hsT, Wc, bc, zbias);

    // D2: dt blocks first, then zb GEMM blocks (co-residency overlap)
    d2_kernel<<<1024 + 544, 256, 0, stream>>>(
        hsT, Wfuse, zbias, Wc, bc, zb, dtf);

    // D3: fused conv + SSD + gate -> gb + part
    ssd_kernel<<<dim3(NSEQ, 4), 256, 0, stream>>>(
        zb, dtf, conv_w, conv_b, dt_bias, A_log, Dp, gb, part);

    // D4: out = colscale(part) * (Wbig . gb^T) + pob   (R16 shape)
    k67_gemm<<<dim3(4, 64), 256, 0, stream>>>(
        Wbig, gb, proj_out_b, part, out);
}

// Round 19
// 97.658 us; speedup vs baseline: 1.0526x; 1.0398x over previous
//
#include <hip/hip_runtime.h>
#include <hip/hip_bf16.h>
#include <math.h>

// Problem constants
#define TT       16
#define NSEQ     256
#define TOK      4096
#define DMODEL   512
#define DINNER   1024
#define DSTATE   64
#define NHEADS   16
#define HEADDIM  64
#define DINPROJ  2192
#define DTOFF    2176
#define ZLD      2176    // zb row stride (z:0..1023, x:1024..2047, BC:2048..2175)

using bf16x8 = __attribute__((ext_vector_type(8))) short;
using f32x4  = __attribute__((ext_vector_type(4))) float;
typedef __hip_bfloat16 bf16;

__device__ __forceinline__ void gload_lds16(const void* g, void* l) {
    __builtin_amdgcn_global_load_lds(
        (const __attribute__((address_space(1))) unsigned int*)g,
        (__attribute__((address_space(3))) unsigned int*)l,
        16, 0, 0);
}

// ---------------------------------------------------------------------------
// GEMM core (bf16 sources via global_load_lds):
// C[M][N] = A[M][K]*B[N][K]^T (+ bias[col]), bf16 out.
// Tile 128 x (NFRAG*32), BK=32, 256 threads (4 waves, 2x2 wave grid).
// ---------------------------------------------------------------------------
template<int NFRAG>
__device__ __forceinline__ void gemm_core(
    short* As, short* Bs,
    const bf16* __restrict__ A, const bf16* __restrict__ B,
    const float* __restrict__ bias, bf16* __restrict__ Ch,
    int bm, int bn, int K, int lda, int ldb, int ldc, int Nreal)
{
    constexpr int BN = NFRAG * 32;
    const int tid = threadIdx.x;
    const int wv = tid >> 6, ln = tid & 63;
    const int m0 = bm * 128, n0 = bn * BN;
    const int wr = wv >> 1, wc = wv & 1;
    const int lr = ln & 15, lk = (ln >> 4) * 8;

    f32x4 acc[4][NFRAG];
#pragma unroll
    for (int m = 0; m < 4; ++m)
#pragma unroll
        for (int n = 0; n < NFRAG; ++n) acc[m][n] = (f32x4){0.f, 0.f, 0.f, 0.f};

    for (int k0 = 0; k0 < K; k0 += 32) {
        __syncthreads();
#pragma unroll
        for (int r = 0; r < 2; ++r) {
            const int ofs = r * 4096 + tid * 16;
            const int row = ofs >> 6, ke = (ofs & 63) >> 1;
            gload_lds16(A + (size_t)(m0 + row) * lda + k0 + ke, (char*)As + ofs);
        }
#pragma unroll
        for (int r = 0; r < NFRAG / 2; ++r) {
            const int ofs = r * 4096 + tid * 16;
            const int row = ofs >> 6, ke = (ofs & 63) >> 1;
            gload_lds16(B + (size_t)(n0 + row) * ldb + k0 + ke, (char*)Bs + ofs);
        }
        __syncthreads();

        bf16x8 af[4], bfr[NFRAG];
#pragma unroll
        for (int m = 0; m < 4; ++m)
            af[m] = *(const bf16x8*)&As[(wr * 64 + m * 16 + lr) * 32 + lk];
#pragma unroll
        for (int n = 0; n < NFRAG; ++n)
            bfr[n] = *(const bf16x8*)&Bs[(wc * (BN / 2) + n * 16 + lr) * 32 + lk];
#pragma unroll
        for (int m = 0; m < 4; ++m)
#pragma unroll
            for (int n = 0; n < NFRAG; ++n)
                acc[m][n] = __builtin_amdgcn_mfma_f32_16x16x32_bf16(
                    af[m], bfr[n], acc[m][n], 0, 0, 0);
    }

    const int mBase = m0 + wr * 64, nBase = n0 + wc * (BN / 2);
    float cbv[NFRAG];
#pragma unroll
    for (int n = 0; n < NFRAG; ++n) {
        const int col = nBase + n * 16 + lr;
        cbv[n] = (bias != nullptr && col < Nreal) ? bias[col] : 0.f;
    }
#pragma unroll
    for (int m = 0; m < 4; ++m) {
#pragma unroll
        for (int j = 0; j < 4; ++j) {
            const int row = mBase + m * 16 + (ln >> 4) * 4 + j;
#pragma unroll
            for (int n = 0; n < NFRAG; ++n) {
                const int col = nBase + n * 16 + lr;
                if (col < Nreal)
                    Ch[(size_t)row * ldc + col] =
                        __float2bfloat16(acc[m][n][j] + cbv[n]);
            }
        }
    }
}

// ---------------------------------------------------------------------------
// GEMM core with fp32 sources (register-staged, converted to bf16 in-flight):
//   A(m,k) = A[(m0+m)*lda + k]                         (fp32 row-major)
//   B(n,k) = Bsrc[k*ldb + n0+n] * (SCALE? scale[n0+n]) (fp32 TRANSPOSED src)
// C bf16 out, no bias. Tile 128 x 64 (NFRAG=2), BK=32.
// ---------------------------------------------------------------------------
template<bool SCALE>
__device__ __forceinline__ void gemm_f32t(
    short* As, short* Bs,
    const float* __restrict__ A, const float* __restrict__ Bsrc,
    const float* __restrict__ scale, bf16* __restrict__ Ch,
    int bm, int bn, int K, int lda, int ldb, int ldc)
{
    const int tid = threadIdx.x;
    const int wv = tid >> 6, ln = tid & 63;
    const int m0 = bm * 128, n0 = bn * 64;
    const int wr = wv >> 1, wc = wv & 1;
    const int lr = ln & 15, lk = (ln >> 4) * 8;

    const int bn_row = tid >> 2;
    const float bscale = SCALE ? scale[n0 + bn_row] : 1.f;

    f32x4 acc[4][2];
#pragma unroll
    for (int m = 0; m < 4; ++m)
#pragma unroll
        for (int n = 0; n < 2; ++n) acc[m][n] = (f32x4){0.f, 0.f, 0.f, 0.f};

    for (int k0 = 0; k0 < K; k0 += 32) {
        __syncthreads();
        {   // A tile: thread -> row tid>>1, k-offset (tid&1)*16 (4x float4)
            const int row = tid >> 1, koff = (tid & 1) * 16;
            const float* src = A + (size_t)(m0 + row) * lda + k0 + koff;
#pragma unroll
            for (int q = 0; q < 4; ++q) {
                const float4 v = *(const float4*)(src + q * 4);
                As[row * 32 + koff + q * 4 + 0] = (short)__bfloat16_as_ushort(__float2bfloat16(v.x));
                As[row * 32 + koff + q * 4 + 1] = (short)__bfloat16_as_ushort(__float2bfloat16(v.y));
                As[row * 32 + koff + q * 4 + 2] = (short)__bfloat16_as_ushort(__float2bfloat16(v.z));
                As[row * 32 + koff + q * 4 + 3] = (short)__bfloat16_as_ushort(__float2bfloat16(v.w));
            }
        }
        {   // B tile: thread -> row tid>>2, k-offset (tid&3)*8 (strided src)
            const int n = bn_row, koff = (tid & 3) * 8;
#pragma unroll
            for (int j = 0; j < 8; ++j) {
                const float v = Bsrc[(size_t)(k0 + koff + j) * ldb + n0 + n] * bscale;
                Bs[n * 32 + koff + j] = (short)__bfloat16_as_ushort(__float2bfloat16(v));
            }
        }
        __syncthreads();

        bf16x8 af[4], bfr[2];
#pragma unroll
        for (int m = 0; m < 4; ++m)
            af[m] = *(const bf16x8*)&As[(wr * 64 + m * 16 + lr) * 32 + lk];
#pragma unroll
        for (int n = 0; n < 2; ++n)
            bfr[n] = *(const bf16x8*)&Bs[(wc * 32 + n * 16 + lr) * 32 + lk];
#pragma unroll
        for (int m = 0; m < 4; ++m)
#pragma unroll
            for (int n = 0; n < 2; ++n)
                acc[m][n] = __builtin_amdgcn_mfma_f32_16x16x32_bf16(
                    af[m], bfr[n], acc[m][n], 0, 0, 0);
    }

    const int mBase = m0 + wr * 64, nBase = n0 + wc * 32;
#pragma unroll
    for (int m = 0; m < 4; ++m) {
#pragma unroll
        for (int j = 0; j < 4; ++j) {
            const int row = mBase + m * 16 + (ln >> 4) * 4 + j;
#pragma unroll
            for (int n = 0; n < 2; ++n) {
                const int col = nBase + n * 16 + lr;
                Ch[(size_t)row * ldc + col] = __float2bfloat16(acc[m][n][j]);
            }
        }
    }
}

// ---------------------------------------------------------------------------
// D1: Wfuse/Wbig GEMMs (fp32 sources) + prep (Wc/bc, zbias, hsT).
//  [0,136):     Wfuse[e][c] = sum_d ip[e][d]*pi[d][c]      (17 x 8 tiles)
//  [136,200):   Wbig[c][d]  = sum_o po[c][o]*op[o][d]*nw[d] (4 x 16 tiles)
//  [200,328):   Wc[h][c] fp32 (+bc)
//  [328,872):   zbias[e] = pib . ip[e]
//  [872,2920):  hsT[v][c] = bf16(hs[c][v])
// ---------------------------------------------------------------------------
#define NB_D1  2920

__global__ __launch_bounds__(256) void d1_kernel(
    const float* __restrict__ pi, const float* __restrict__ po,
    const float* __restrict__ op, const float* __restrict__ ip,
    const float* __restrict__ nw, const float* __restrict__ pib,
    const float* __restrict__ hs,
    bf16* __restrict__ Wfuse, bf16* __restrict__ Wbig, bf16* __restrict__ hsT,
    float* __restrict__ Wc, float* __restrict__ bc, float* __restrict__ zbias)
{
    __shared__ __align__(16) char smemraw[16384];
    const int b = blockIdx.x, tid = threadIdx.x;

    if (b < 136) {
        short* As = (short*)smemraw;
        short* Bs = As + 4096;
        gemm_f32t<false>(As, Bs, ip, pi, nullptr, Wfuse,
                         b >> 3, b & 7, DMODEL, DMODEL, DMODEL, DMODEL);
    } else if (b < 200) {
        short* As = (short*)smemraw;
        short* Bs = As + 4096;
        const int u = b - 136;
        gemm_f32t<true>(As, Bs, po, op, nw, Wbig,
                        u & 3, u >> 2, DMODEL, DMODEL, DINNER, DINNER);
    } else if (b < 328) {
        float* smem = (float*)smemraw;
        const int b2 = b - 200;
        const int h = b2 >> 3, c0 = (b2 & 7) * 64;
        const int w = tid >> 6, l = tid & 63;
        const float* wdt = ip + (size_t)(DTOFF + h) * DMODEL;
        float acc = 0.f;
#pragma unroll 8
        for (int i = 0; i < 128; ++i) {
            const int d = w * 128 + i;
            acc = fmaf(wdt[d], pi[(size_t)d * DMODEL + c0 + l], acc);
        }
        smem[w * 64 + l] = acc;
        __syncthreads();
        if (tid < 64)
            Wc[(size_t)h * DMODEL + c0 + tid] =
                smem[tid] + smem[64 + tid] + smem[128 + tid] + smem[192 + tid];
        if ((b2 & 7) == 0) {
            float p = pib[tid] * wdt[tid] + pib[tid + 256] * wdt[tid + 256];
#pragma unroll
            for (int off = 32; off >= 1; off >>= 1) p += __shfl_xor(p, off);
            if ((tid & 63) == 0) smem[300 + (tid >> 6)] = p;
            __syncthreads();
            if (tid == 0)
                bc[h] = smem[300] + smem[301] + smem[302] + smem[303];
        }
    } else if (b < 872) {
        const int e = (b - 328) * 4 + (tid >> 6);
        const int l = tid & 63;
        const float* row = ip + (size_t)e * DMODEL;
        float acc = 0.f;
#pragma unroll
        for (int i = 0; i < 8; ++i)
            acc = fmaf(pib[l + i * 64], row[l + i * 64], acc);
#pragma unroll
        for (int off = 32; off >= 1; off >>= 1) acc += __shfl_xor(acc, off);
        if (l == 0) zbias[e] = acc;
    } else {
        float* smem = (float*)smemraw;
        const int tb = b - 872;
        const int v0 = (tb & 127) * 32, c0 = (tb >> 7) * 32;
        const int tx = tid & 31, ty = tid >> 5;
#pragma unroll
        for (int i = 0; i < 4; ++i)
            smem[(ty + 8 * i) * 33 + tx] =
                hs[(size_t)(c0 + ty + 8 * i) * TOK + v0 + tx];
        __syncthreads();
#pragma unroll
        for (int i = 0; i < 4; ++i)
            hsT[(size_t)(v0 + ty + 8 * i) * DMODEL + c0 + tx] =
                __float2bfloat16(smem[tx * 33 + ty + 8 * i]);
    }
}

// ---------------------------------------------------------------------------
// D2: zb GEMM blocks first, then dt blocks (R16-proven order).
//  [0,544):     zb[v][e] = hsT[v][:] . Wfuse[e][:] + zbias[e]
//  [544,1568):  dt: wave w -> token v = (b-544)*4+w, all 16 heads (fp32 acc)
// ---------------------------------------------------------------------------
__global__ __launch_bounds__(256) void d2_kernel(
    const bf16* __restrict__ hsT, const bf16* __restrict__ Wfuse,
    const float* __restrict__ zbias, const float* __restrict__ Wc,
    const float* __restrict__ bc,
    bf16* __restrict__ zb, float* __restrict__ dtf)
{
    __shared__ __align__(16) char smemraw[16384];
    const int b = blockIdx.x;
    if (b < 544) {
        short* As = (short*)smemraw;
        short* Bs = As + 4096;
        gemm_core<4>(As, Bs, hsT, Wfuse, zbias, zb,
                     b & 31, b >> 5, DMODEL, DMODEL, DMODEL, ZLD, ZLD);
    } else {
        const int tid = threadIdx.x;
        const int w = tid >> 6, l = tid & 63;
        const int v = (b - 544) * 4 + w;
        const bf16x8 hv = *(const bf16x8*)(hsT + (size_t)v * DMODEL + l * 8);
        float hf[8];
#pragma unroll
        for (int j = 0; j < 8; ++j) {
            const unsigned int bits = ((unsigned int)(unsigned short)hv[j]) << 16;
            hf[j] = __uint_as_float(bits);
        }
#pragma unroll
        for (int h = 0; h < 16; ++h) {
            const float4* wr_ = (const float4*)(Wc + (size_t)h * DMODEL);
            const float4 w0 = wr_[l * 2], w1 = wr_[l * 2 + 1];
            float dot = hf[0] * w0.x + hf[1] * w0.y + hf[2] * w0.z + hf[3] * w0.w
                      + hf[4] * w1.x + hf[5] * w1.y + hf[6] * w1.z + hf[7] * w1.w;
#pragma unroll
            for (int off = 32; off >= 1; off >>= 1) dot += __shfl_xor(dot, off);
            if (l == 0) dtf[(size_t)v * 16 + h] = dot + bc[h];
        }
    }
}

// ---------------------------------------------------------------------------
// D3: fused conv + SSD + D-skip + z-gating -> gb (bf16) + partial sumsq.
// Grid (n, hq): 256 x 4 blocks, 256 threads = 4 waves; wave w = head hq*4+w.
// ---------------------------------------------------------------------------
__global__ __launch_bounds__(256) void ssd_kernel(
    const bf16* __restrict__ zb, const float* __restrict__ dtf,
    const float* __restrict__ conv_w, const float* __restrict__ conv_b,
    const float* __restrict__ dt_bias, const float* __restrict__ A_log,
    const float* __restrict__ Dp,
    bf16* __restrict__ gb, float* __restrict__ part)
{
    const int n = blockIdx.x, hq = blockIdx.y;
    const int tid = threadIdx.x;
    const int w = tid >> 6, p = tid & 63;
    const int h = hq * 4 + w;
    const int ch = hq * 256 + tid;

    __shared__ float Bsh[16][68];
    __shared__ float Csh[16][68];
    __shared__ float Gsh[16][16];
    __shared__ float Msh[4][256];
    __shared__ float red4[16][4];

    float ld[16];
#pragma unroll
    for (int t = 0; t < 16; ++t)
        ld[t] = __bfloat162float(zb[(size_t)(t * 256 + n) * ZLD + 1024 + ch]);

    const float cw0 = conv_w[ch * 4 + 0], cw1 = conv_w[ch * 4 + 1],
                cw2 = conv_w[ch * 4 + 2], cw3 = conv_w[ch * 4 + 3];
    const float cb = conv_b[ch];
    float xs[16];
#pragma unroll
    for (int t = 0; t < 16; ++t) {
        float a = fmaf(ld[t], cw3, cb);
        if (t >= 1) a = fmaf(ld[t - 1], cw2, a);
        if (t >= 2) a = fmaf(ld[t - 2], cw1, a);
        if (t >= 3) a = fmaf(ld[t - 3], cw0, a);
        xs[t] = a / (1.f + __expf(-a));
    }

    if (tid < 128) {
        const int cc = 1024 + tid;
        const float dw0 = conv_w[cc * 4 + 0], dw1 = conv_w[cc * 4 + 1],
                    dw2 = conv_w[cc * 4 + 2], dw3 = conv_w[cc * 4 + 3];
        const float db = conv_b[cc];
        float q0 = 0.f, q1 = 0.f, q2 = 0.f;
#pragma unroll
        for (int t = 0; t < 16; ++t) {
            const float cur =
                __bfloat162float(zb[(size_t)(t * 256 + n) * ZLD + 2048 + tid]);
            float a = fmaf(cur, dw3, db);
            a = fmaf(q2, dw2, a);
            a = fmaf(q1, dw1, a);
            a = fmaf(q0, dw0, a);
            const float val = a / (1.f + __expf(-a));
            if (tid < 64) Bsh[t][tid] = val; else Csh[t][tid - 64] = val;
            q0 = q1; q1 = q2; q2 = cur;
        }
    }

    const float a_h = -__expf(A_log[h]);
    float dtv_l = 0.f;
    if (p < 16) {
        const float raw = dtf[(size_t)(p * 256 + n) * 16 + h] + dt_bias[h];
        dtv_l = (raw > 20.f) ? raw : log1pf(__expf(raw));
    }
    float cum_l = dtv_l;
#pragma unroll
    for (int off = 1; off < 16; off <<= 1) {
        const float tmp = __shfl_up(cum_l, off);
        if (p >= off) cum_l += tmp;
    }
    __syncthreads();

    {
        const int t = tid >> 4, s = tid & 15;
        float acc = 0.f;
#pragma unroll
        for (int k = 0; k < 64; ++k)
            acc = fmaf(Csh[t][k], Bsh[s][k], acc);
        Gsh[t][s] = acc;
    }
    __syncthreads();

    float dtv_all[16], cum_all[16];
#pragma unroll
    for (int t = 0; t < 16; ++t) {
        dtv_all[t] = __shfl(dtv_l, t);
        cum_all[t] = __shfl(cum_l, t);
    }
#pragma unroll
    for (int q = 0; q < 4; ++q) {
        const int idx = p * 4 + q;
        const int t = idx >> 4, s = idx & 15;
        float m = 0.f;
        if (s <= t)
            m = __expf(a_h * (cum_all[t] - cum_all[s])) * Gsh[t][s] * dtv_all[s];
        Msh[w][idx] = m;
    }

    float zl[16];
#pragma unroll
    for (int t = 0; t < 16; ++t)
        zl[t] = __bfloat162float(zb[(size_t)(t * 256 + n) * ZLD + ch]);

    const float Dh = Dp[h];
    float g[16];
#pragma unroll
    for (int t = 0; t < 16; ++t) {
        float y = 0.f;
#pragma unroll
        for (int s = 0; s <= t; ++s)
            y = fmaf(Msh[w][t * 16 + s], xs[s], y);
        y = fmaf(Dh, xs[t], y);
        g[t] = y * (zl[t] / (1.f + __expf(-zl[t])));
    }

#pragma unroll
    for (int t = 0; t < 16; ++t) {
        float ss = g[t] * g[t];
#pragma unroll
        for (int off = 32; off >= 1; off >>= 1) ss += __shfl_xor(ss, off);
        if (p == 0) red4[t][w] = ss;
        gb[(size_t)(t * 256 + n) * DINNER + ch] = __float2bfloat16(g[t]);
    }
    __syncthreads();
    if (tid < 16)
        part[(size_t)(tid * 256 + n) * 4 + hq] =
            red4[tid][0] + red4[tid][1] + red4[tid][2] + red4[tid][3];
}

// ---------------------------------------------------------------------------
// D4: out[c][v] = rsqrt(mean part[v] + eps) * (Wbig[c][:] . gb[v][:]) + pob[c]
// fp32 out, row-major = out layout. Tile 128 x 64, grid (4,64) — R16 proven.
// ---------------------------------------------------------------------------
__global__ __launch_bounds__(256) void k67_gemm(
    const bf16* __restrict__ A, const bf16* __restrict__ B,
    const float* __restrict__ bias, const float* __restrict__ rs,
    float* __restrict__ Cf)
{
    __shared__ short As[128 * 32];
    __shared__ short Bs[64 * 32];

    const int tid = threadIdx.x;
    const int wv = tid >> 6, ln = tid & 63;
    const int m0 = blockIdx.x * 128, n0 = blockIdx.y * 64;
    const int wr = wv >> 1, wc = wv & 1;
    const int lr = ln & 15, lk = (ln >> 4) * 8;

    f32x4 acc[4][2];
#pragma unroll
    for (int m = 0; m < 4; ++m)
#pragma unroll
        for (int n = 0; n < 2; ++n) acc[m][n] = (f32x4){0.f, 0.f, 0.f, 0.f};

    for (int k0 = 0; k0 < DINNER; k0 += 32) {
        __syncthreads();
#pragma unroll
        for (int r = 0; r < 2; ++r) {
            const int ofs = r * 4096 + tid * 16;
            const int row = ofs >> 6, ke = (ofs & 63) >> 1;
            gload_lds16(A + (size_t)(m0 + row) * DINNER + k0 + ke, (char*)As + ofs);
        }
        {
            const int ofs = tid * 16;
            const int row = ofs >> 6, ke = (ofs & 63) >> 1;
            gload_lds16(B + (size_t)(n0 + row) * DINNER + k0 + ke, (char*)Bs + ofs);
        }
        __syncthreads();

        bf16x8 af[4], bfr[2];
#pragma unroll
        for (int m = 0; m < 4; ++m)
            af[m] = *(const bf16x8*)&As[(wr * 64 + m * 16 + lr) * 32 + lk];
#pragma unroll
        for (int n = 0; n < 2; ++n)
            bfr[n] = *(const bf16x8*)&Bs[(wc * 32 + n * 16 + lr) * 32 + lk];
#pragma unroll
        for (int m = 0; m < 4; ++m)
#pragma unroll
            for (int n = 0; n < 2; ++n)
                acc[m][n] = __builtin_amdgcn_mfma_f32_16x16x32_bf16(
                    af[m], bfr[n], acc[m][n], 0, 0, 0);
    }

    const int mBase = m0 + wr * 64, nBase = n0 + wc * 32;
    float scn[2];
#pragma unroll
    for (int n = 0; n < 2; ++n) {
        const int col = nBase + n * 16 + lr;
        const float4 pv = *(const float4*)(rs + (size_t)col * 4);
        scn[n] = rsqrtf((pv.x + pv.y + pv.z + pv.w) * (1.f / 1024.f) + 1e-5f);
    }
#pragma unroll
    for (int m = 0; m < 4; ++m) {
#pragma unroll
        for (int j = 0; j < 4; ++j) {
            const int row = mBase + m * 16 + (ln >> 4) * 4 + j;
            const float rb = bias[row];
#pragma unroll
            for (int n = 0; n < 2; ++n) {
                const int col = nBase + n * 16 + lr;
                Cf[(size_t)row * TOK + col] = acc[m][n][j] * scn[n] + rb;
            }
        }
    }
}

// ---------------------------------------------------------------------------
extern "C" void kernel_launch(void* const* d_in, const int* in_sizes, int n_in,
                              void* d_out, int out_size, void* d_ws, size_t ws_size,
                              hipStream_t stream) {
    const float* hs         = (const float*)d_in[0];
    const float* proj_in_w  = (const float*)d_in[1];
    const float* proj_in_b  = (const float*)d_in[2];
    const float* proj_out_w = (const float*)d_in[3];
    const float* proj_out_b = (const float*)d_in[4];
    const float* in_proj_w  = (const float*)d_in[5];
    const float* conv_w     = (const float*)d_in[6];
    const float* conv_b     = (const float*)d_in[7];
    const float* dt_bias    = (const float*)d_in[8];
    const float* A_log      = (const float*)d_in[9];
    const float* Dp         = (const float*)d_in[10];
    const float* norm_w     = (const float*)d_in[11];
    const float* out_proj_w = (const float*)d_in[12];
    float* out = (float*)d_out;

    // workspace layout (fp32 first, then bf16)
    float* ws    = (float*)d_ws;
    float* dtf   = ws;                                  // 4096*16 f32
    float* part  = dtf + (size_t)TOK * 16;              // 4096*4  f32
    float* Wc    = part + (size_t)TOK * 4;              // 16*512  f32
    float* bc    = Wc + 16 * DMODEL;                    // 16      f32
    float* zbias = bc + 16;                             // 2176    f32
    bf16*  hsT   = (bf16*)(zbias + ZLD);                // 4096*512
    bf16*  zb    = hsT + (size_t)TOK * DMODEL;          // 4096*2176
    bf16*  gb    = zb + (size_t)TOK * ZLD;              // 4096*1024
    bf16*  Wfuse = gb + (size_t)TOK * DINNER;           // 2176*512
    bf16*  Wbig  = Wfuse + (size_t)ZLD * DMODEL;        // 512*1024

    // D1: W-product GEMMs (fp32 sources) + Wc/bc/zbias + hsT transpose
    d1_kernel<<<NB_D1, 256, 0, stream>>>(
        proj_in_w, proj_out_w, out_proj_w, in_proj_w, norm_w, proj_in_b, hs,
        Wfuse, Wbig, hsT, Wc, bc, zbias);

    // D2: zb = hsT . Wfuse^T + zbias (bf16)  and  dtf = hsT . Wc^T + bc (fp32)
    d2_kernel<<<544 + 1024, 256, 0, stream>>>(
        hsT, Wfuse, zbias, Wc, bc, zb, dtf);

    // D3: fused conv + SSD + gate -> gb + part
    ssd_kernel<<<dim3(NSEQ, 4), 256, 0, stream>>>(
        zb, dtf, conv_w, conv_b, dt_bias, A_log, Dp, gb, part);

    // D4: out = colscale(part) * (Wbig . gb^T) + pob   (R16 shape)
    k67_gemm<<<dim3(4, 64), 256, 0, stream>>>(
        Wbig, gb, proj_out_b, part, out);
}